// Round 1
// baseline (373.308 us; speedup 1.0000x reference)
//
#include <hip/hip_runtime.h>
#include <float.h>

#define NN 50000
#define EE 800000

// ---------- prep: Wp = post_W @ lin_W  [512,128]; bp = post_b @ lin_W + lin_b ----------
__global__ __launch_bounds__(256) void k_prep(const float* __restrict__ post_W,
    const float* __restrict__ post_b, const float* __restrict__ lin_W,
    const float* __restrict__ lin_b, float* __restrict__ Wp, float* __restrict__ bp) {
  int idx = blockIdx.x * 256 + threadIdx.x;
  if (idx < 512 * 128) {
    int i = idx >> 7, j = idx & 127;
    float s = 0.f;
#pragma unroll 8
    for (int k = 0; k < 128; k++) s += post_W[i * 128 + k] * lin_W[k * 128 + j];
    Wp[idx] = s;
  } else if (idx < 512 * 128 + 128) {
    int j = idx - 512 * 128;
    float s = lin_b[j];
    for (int k = 0; k < 128; k++) s += post_b[k] * lin_W[k * 128 + j];
    bp[j] = s;
  }
}

// ---------- GEMM: PQ[N,256] = x[N,128] @ [W1 | W2]  (W1=preW rows 0..127, W2=rows 128..255) ----------
__global__ __launch_bounds__(256) void k_gemm_pq(const float* __restrict__ x,
    const float* __restrict__ preW, float* __restrict__ PQ) {
  __shared__ __align__(16) float As[32][68];
  __shared__ __align__(16) float Bs[32][64];
  const int row0 = blockIdx.x * 64;
  const int n0 = blockIdx.y * 64;
  const int t = threadIdx.x;
  const int tx = t & 15, ty = t >> 4;
  // column j of PQ: j<128 -> preW[k*128+j] ; j>=128 -> preW[(128+k)*128 + (j-128)]
  const float* Bsrc = (n0 < 128) ? (preW + n0) : (preW + 128 * 128 + (n0 - 128));
  float acc[4][4] = {};
  for (int k0 = 0; k0 < 128; k0 += 32) {
    {
      const int ar = t >> 3;
      const int ak = (t & 7) << 2;
#pragma unroll
      for (int p = 0; p < 2; p++) {
        int m = ar + p * 32;
        int gr = row0 + m;
        float4 v = make_float4(0.f, 0.f, 0.f, 0.f);
        if (gr < NN) v = *(const float4*)(x + gr * 128 + k0 + ak);
        As[ak + 0][m] = v.x; As[ak + 1][m] = v.y; As[ak + 2][m] = v.z; As[ak + 3][m] = v.w;
      }
      const int bn = (t & 15) << 2;
      const int bk = t >> 4;
#pragma unroll
      for (int p = 0; p < 2; p++) {
        int kk = bk + p * 16;
        *(float4*)&Bs[kk][bn] = *(const float4*)(Bsrc + (k0 + kk) * 128 + bn);
      }
    }
    __syncthreads();
#pragma unroll
    for (int k = 0; k < 32; k++) {
      float4 a4 = *(const float4*)&As[k][ty << 2];
      float4 b4 = *(const float4*)&Bs[k][tx << 2];
      float av[4] = {a4.x, a4.y, a4.z, a4.w};
      float bv[4] = {b4.x, b4.y, b4.z, b4.w};
#pragma unroll
      for (int i = 0; i < 4; i++)
#pragma unroll
        for (int j = 0; j < 4; j++) acc[i][j] += av[i] * bv[j];
    }
    __syncthreads();
  }
#pragma unroll
  for (int i = 0; i < 4; i++) {
    int gr = row0 + (ty << 2) + i;
    if (gr < NN) {
      float4 v = make_float4(acc[i][0], acc[i][1], acc[i][2], acc[i][3]);
      *(float4*)(PQ + gr * 256 + n0 + (tx << 2)) = v;
    }
  }
}

// ---------- GEMM: out[N,128] = relu([x | aggr] @ Wp + bp) ----------
__global__ __launch_bounds__(256) void k_gemm_out(const float* __restrict__ x,
    const float* __restrict__ aggr, const float* __restrict__ Wp,
    const float* __restrict__ bp, float* __restrict__ out) {
  __shared__ __align__(16) float As[32][68];
  __shared__ __align__(16) float Bs[32][64];
  const int row0 = blockIdx.x * 64;
  const int n0 = blockIdx.y * 64;
  const int t = threadIdx.x;
  const int tx = t & 15, ty = t >> 4;
  float acc[4][4] = {};
  for (int k0 = 0; k0 < 512; k0 += 32) {
    const float* Asrc;
    int lda, kc;
    if (k0 < 128) { Asrc = x; lda = 128; kc = k0; }
    else          { Asrc = aggr; lda = 384; kc = k0 - 128; }
    {
      const int ar = t >> 3;
      const int ak = (t & 7) << 2;
#pragma unroll
      for (int p = 0; p < 2; p++) {
        int m = ar + p * 32;
        int gr = row0 + m;
        float4 v = make_float4(0.f, 0.f, 0.f, 0.f);
        if (gr < NN) v = *(const float4*)(Asrc + (size_t)gr * lda + kc + ak);
        As[ak + 0][m] = v.x; As[ak + 1][m] = v.y; As[ak + 2][m] = v.z; As[ak + 3][m] = v.w;
      }
      const int bn = (t & 15) << 2;
      const int bk = t >> 4;
#pragma unroll
      for (int p = 0; p < 2; p++) {
        int kk = bk + p * 16;
        *(float4*)&Bs[kk][bn] = *(const float4*)(Wp + (k0 + kk) * 128 + n0 + bn);
      }
    }
    __syncthreads();
#pragma unroll
    for (int k = 0; k < 32; k++) {
      float4 a4 = *(const float4*)&As[k][ty << 2];
      float4 b4 = *(const float4*)&Bs[k][tx << 2];
      float av[4] = {a4.x, a4.y, a4.z, a4.w};
      float bv[4] = {b4.x, b4.y, b4.z, b4.w};
#pragma unroll
      for (int i = 0; i < 4; i++)
#pragma unroll
        for (int j = 0; j < 4; j++) acc[i][j] += av[i] * bv[j];
    }
    __syncthreads();
  }
#pragma unroll
  for (int i = 0; i < 4; i++) {
    int gr = row0 + (ty << 2) + i;
    if (gr < NN) {
      int col = n0 + (tx << 2);
      float4 v;
      v.x = fmaxf(acc[i][0] + bp[col + 0], 0.f);
      v.y = fmaxf(acc[i][1] + bp[col + 1], 0.f);
      v.z = fmaxf(acc[i][2] + bp[col + 2], 0.f);
      v.w = fmaxf(acc[i][3] + bp[col + 3], 0.f);
      *(float4*)(out + gr * 128 + col) = v;
    }
  }
}

// ---------- CSR build ----------
__global__ void k_hist(const int* __restrict__ ei, int* __restrict__ cnt) {
  int e = blockIdx.x * 256 + threadIdx.x;
  if (e < EE) atomicAdd(&cnt[ei[EE + e]], 1);
}

__global__ void k_blocksum(const int* __restrict__ cnt, int* __restrict__ bsum) {
  __shared__ int sdata[256];
  int i = blockIdx.x * 256 + threadIdx.x;
  sdata[threadIdx.x] = (i < NN) ? cnt[i] : 0;
  __syncthreads();
  for (int s = 128; s > 0; s >>= 1) {
    if (threadIdx.x < s) sdata[threadIdx.x] += sdata[threadIdx.x + s];
    __syncthreads();
  }
  if (threadIdx.x == 0) bsum[blockIdx.x] = sdata[0];
}

__global__ void k_scanbsum(int* bsum, int nb) {
  if (blockIdx.x == 0 && threadIdx.x == 0) {
    int acc = 0;
    for (int b = 0; b < nb; b++) { int v = bsum[b]; bsum[b] = acc; acc += v; }
  }
}

__global__ void k_rowptr(const int* __restrict__ cnt, const int* __restrict__ bsum,
                         int* __restrict__ row_ptr, int* __restrict__ cursor) {
  __shared__ int sdata[256];
  int i = blockIdx.x * 256 + threadIdx.x;
  int v = (i < NN) ? cnt[i] : 0;
  sdata[threadIdx.x] = v;
  __syncthreads();
  for (int s = 1; s < 256; s <<= 1) {
    int tval = (threadIdx.x >= s) ? sdata[threadIdx.x - s] : 0;
    __syncthreads();
    sdata[threadIdx.x] += tval;
    __syncthreads();
  }
  int excl = sdata[threadIdx.x] - v + bsum[blockIdx.x];
  if (i < NN) { row_ptr[i] = excl; cursor[i] = excl; }
  if (i == NN - 1) row_ptr[NN] = excl + v;
}

__global__ void k_fill(const int* __restrict__ ei, int* __restrict__ cursor,
                       int* __restrict__ csr_src) {
  int e = blockIdx.x * 256 + threadIdx.x;
  if (e < EE) {
    int d = ei[EE + e];
    int pos = atomicAdd(&cursor[d], 1);
    csr_src[pos] = ei[e];
  }
}

// ---------- aggregation: one wave per node ----------
__global__ __launch_bounds__(256) void k_aggr(const float* __restrict__ PQ,
    const float* __restrict__ pre_b, const int* __restrict__ row_ptr,
    const int* __restrict__ csr_src, float* __restrict__ aggr) {
  int wid = (blockIdx.x * 256 + threadIdx.x) >> 6;
  int lane = threadIdx.x & 63;
  if (wid >= NN) return;
  int r0 = row_ptr[wid], r1 = row_ptr[wid + 1];
  int c = lane * 2;
  float sx = 0.f, sy = 0.f;
  float mxx = -FLT_MAX, mxy = -FLT_MAX;
  for (int i = r0; i < r1; i++) {
    int s = csr_src[i];
    float2 q = *(const float2*)(PQ + (size_t)s * 256 + 128 + c);
    sx += q.x; sy += q.y;
    mxx = fmaxf(mxx, q.x); mxy = fmaxf(mxy, q.y);
  }
  float2 P = *(const float2*)(PQ + (size_t)wid * 256 + c);
  float2 b = *(const float2*)(pre_b + c);
  float px = P.x + b.x, py = P.y + b.y;
  int deg = r1 - r0;
  float2 vmean, vmax, vsum;
  if (deg > 0) {
    float inv = 1.0f / (float)deg;
    vmean = make_float2(px + sx * inv, py + sy * inv);
    vmax  = make_float2(px + mxx, py + mxy);
    vsum  = make_float2((float)deg * px + sx, (float)deg * py + sy);
  } else {
    vmean = make_float2(0.f, 0.f);
    vmax  = make_float2(0.f, 0.f);
    vsum  = make_float2(0.f, 0.f);
  }
  float* arow = aggr + (size_t)wid * 384;
  *(float2*)(arow + c)       = vmean;
  *(float2*)(arow + 128 + c) = vmax;
  *(float2*)(arow + 256 + c) = vsum;
}

extern "C" void kernel_launch(void* const* d_in, const int* in_sizes, int n_in,
                              void* d_out, int out_size, void* d_ws, size_t ws_size,
                              hipStream_t stream) {
  const float* x      = (const float*)d_in[0];
  const int*   ei     = (const int*)d_in[1];   // [0..E)=src, [E..2E)=dst
  const float* pre_W  = (const float*)d_in[2];
  const float* pre_b  = (const float*)d_in[3];
  const float* post_W = (const float*)d_in[4];
  const float* post_b = (const float*)d_in[5];
  const float* lin_W  = (const float*)d_in[6];
  const float* lin_b  = (const float*)d_in[7];
  float* out = (float*)d_out;

  char* ws = (char*)d_ws;
  size_t off = 0;
  auto alloc = [&](size_t bytes) { size_t o = off; off = (off + bytes + 511) & ~(size_t)511; return o; };
  float* PQ      = (float*)(ws + alloc((size_t)NN * 256 * 4));
  float* aggr    = (float*)(ws + alloc((size_t)NN * 384 * 4));
  float* Wp      = (float*)(ws + alloc(512 * 128 * 4));
  float* bp      = (float*)(ws + alloc(128 * 4));
  int*   cnt     = (int*)(ws + alloc((size_t)NN * 4));
  int*   row_ptr = (int*)(ws + alloc((size_t)(NN + 1) * 4));
  int*   cursor  = (int*)(ws + alloc((size_t)NN * 4));
  int*   bsum    = (int*)(ws + alloc(256 * 4));
  int*   csr_src = (int*)(ws + alloc((size_t)EE * 4));
  (void)ws_size; (void)in_sizes; (void)n_in; (void)out_size;

  const int NB_N = (NN + 255) / 256;       // 196
  const int NB_E = (EE + 255) / 256;       // 3125

  hipMemsetAsync(cnt, 0, (size_t)NN * 4, stream);
  k_prep<<<(512 * 128 + 128 + 255) / 256, 256, 0, stream>>>(post_W, post_b, lin_W, lin_b, Wp, bp);
  k_gemm_pq<<<dim3((NN + 63) / 64, 4), 256, 0, stream>>>(x, pre_W, PQ);
  k_hist<<<NB_E, 256, 0, stream>>>(ei, cnt);
  k_blocksum<<<NB_N, 256, 0, stream>>>(cnt, bsum);
  k_scanbsum<<<1, 1, 0, stream>>>(bsum, NB_N);
  k_rowptr<<<NB_N, 256, 0, stream>>>(cnt, bsum, row_ptr, cursor);
  k_fill<<<NB_E, 256, 0, stream>>>(ei, cursor, csr_src);
  k_aggr<<<(NN * 64 + 255) / 256, 256, 0, stream>>>(PQ, pre_b, row_ptr, csr_src, aggr);
  k_gemm_out<<<dim3((NN + 63) / 64, 2), 256, 0, stream>>>(x, aggr, Wp, bp, out);
}

// Round 2
// 243.554 us; speedup vs baseline: 1.5327x; 1.5327x over previous
//
#include <hip/hip_runtime.h>
#include <float.h>

#define NN 50000
#define EE 800000

typedef __attribute__((ext_vector_type(8))) short bf16x8;
typedef __attribute__((ext_vector_type(4))) float f32x4;
typedef unsigned short u16;
typedef unsigned int u32;

__device__ __forceinline__ u16 f2bf(float f) {
  u32 u = __builtin_bit_cast(u32, f);
  u32 r = (u + 0x7fffu + ((u >> 16) & 1u)) >> 16;
  return (u16)r;
}
__device__ __forceinline__ float bf2f(u16 h) {
  u32 u = ((u32)h) << 16;
  return __builtin_bit_cast(float, u);
}

// ---------- prep: WpT[128][512] bf16 = (post_W @ lin_W)^T ; WpqT[256][128] bf16 = preW^T-reorg ; bp fp32 ----------
__global__ __launch_bounds__(256) void k_prep(const float* __restrict__ post_W,
    const float* __restrict__ post_b, const float* __restrict__ lin_W,
    const float* __restrict__ lin_b, const float* __restrict__ pre_W,
    u16* __restrict__ WpT, u16* __restrict__ WpqT, float* __restrict__ bp) {
  int idx = blockIdx.x * 256 + threadIdx.x;
  if (idx < 512 * 128) {
    int i = idx >> 7, j = idx & 127;  // Wp[i][j], i=k-row 0..511, j=out-col
    float s = 0.f;
#pragma unroll 8
    for (int c = 0; c < 128; c++) s += post_W[i * 128 + c] * lin_W[c * 128 + j];
    WpT[j * 512 + i] = f2bf(s);
  } else if (idx < 512 * 128 + 256 * 128) {
    int u = idx - 512 * 128;
    int j = u >> 7, k = u & 127;  // WpqT[j][k]
    float v = (j < 128) ? pre_W[k * 128 + j] : pre_W[(128 + k) * 128 + (j - 128)];
    WpqT[j * 128 + k] = f2bf(v);
  } else if (idx < 512 * 128 + 256 * 128 + 128) {
    int j = idx - (512 * 128 + 256 * 128);
    float s = lin_b[j];
    for (int c = 0; c < 128; c++) s += post_b[c] * lin_W[c * 128 + j];
    bp[j] = s;
  }
}

// ---------- convert x -> bf16 into Xcat[:, 0:128] (Xcat is [NN][512]) ----------
__global__ __launch_bounds__(256) void k_convert_x(const float* __restrict__ x,
                                                   u16* __restrict__ Xcat) {
  int tid = blockIdx.x * 256 + threadIdx.x;  // NN*16 = 800000 threads, 8 elems each
  if (tid >= NN * 16) return;
  int row = tid >> 4;
  int col = (tid & 15) << 3;
  const float4 v0 = *(const float4*)(x + (size_t)row * 128 + col);
  const float4 v1 = *(const float4*)(x + (size_t)row * 128 + col + 4);
  u16 tmp[8] = {f2bf(v0.x), f2bf(v0.y), f2bf(v0.z), f2bf(v0.w),
                f2bf(v1.x), f2bf(v1.y), f2bf(v1.z), f2bf(v1.w)};
  *(bf16x8*)(Xcat + (size_t)row * 512 + col) = *(bf16x8*)tmp;
}

// ---------- MFMA GEMM helpers: K-major swizzled LDS tiles [128 rows][64 k] ----------
template <int KTOT, int LDA>
__device__ __forceinline__ void stage_tiles(const u16* __restrict__ A,
    const u16* __restrict__ BT, int row0, int n0, int k0,
    u16* __restrict__ As, u16* __restrict__ Bs, int t) {
#pragma unroll
  for (int it = 0; it < 4; ++it) {
    int c = t + it * 256;            // 1024 chunks of 8 bf16
    int row = c >> 3, ch = c & 7;
    int gr = row0 + row;
    bf16x8 v = {};
    if (gr < NN) v = *(const bf16x8*)(A + (size_t)gr * LDA + k0 + (ch << 3));
    *(bf16x8*)(As + row * 64 + ((ch ^ (row & 7)) << 3)) = v;
  }
#pragma unroll
  for (int it = 0; it < 4; ++it) {
    int c = t + it * 256;
    int n = c >> 3, ch = c & 7;
    bf16x8 v = *(const bf16x8*)(BT + (size_t)(n0 + n) * KTOT + k0 + (ch << 3));
    *(bf16x8*)(Bs + n * 64 + ((ch ^ (n & 7)) << 3)) = v;
  }
}

__device__ __forceinline__ bf16x8 ld_frag(const u16* __restrict__ S, int rowbase,
                                          int kk, int lane) {
  int r = rowbase + (lane & 15);
  int chunk = (kk >> 3) + (lane >> 4);
  int sw = chunk ^ (r & 7);
  return *(const bf16x8*)(S + r * 64 + (sw << 3));
}

// ---------- GEMM: PQb[N,256] bf16 = Xcat[:,0:128] @ WpqT^T ----------
__global__ __launch_bounds__(256) void k_gemm_pq(const u16* __restrict__ Xcat,
    const u16* __restrict__ WpqT, u16* __restrict__ PQb) {
  __shared__ u16 As[128 * 64];
  __shared__ u16 Bs[128 * 64];
  const int t = threadIdx.x;
  const int lane = t & 63, wid = t >> 6;
  const int wr = wid >> 1, wc = wid & 1;
  const int row0 = blockIdx.x * 128;
  const int n0 = blockIdx.y * 128;
  f32x4 acc[4][4] = {};
  for (int k0 = 0; k0 < 128; k0 += 64) {
    stage_tiles<128, 512>(Xcat, WpqT, row0, n0, k0, As, Bs, t);
    __syncthreads();
#pragma unroll
    for (int kk = 0; kk < 64; kk += 32) {
      bf16x8 af[4], bg[4];
#pragma unroll
      for (int m = 0; m < 4; ++m) af[m] = ld_frag(As, wr * 64 + m * 16, kk, lane);
#pragma unroll
      for (int n = 0; n < 4; ++n) bg[n] = ld_frag(Bs, wc * 64 + n * 16, kk, lane);
#pragma unroll
      for (int m = 0; m < 4; ++m)
#pragma unroll
        for (int n = 0; n < 4; ++n)
          acc[m][n] = __builtin_amdgcn_mfma_f32_16x16x32_bf16(af[m], bg[n], acc[m][n], 0, 0, 0);
    }
    __syncthreads();
  }
#pragma unroll
  for (int m = 0; m < 4; ++m) {
    int rb = row0 + wr * 64 + m * 16 + ((lane >> 4) << 2);
#pragma unroll
    for (int n = 0; n < 4; ++n) {
      int col = n0 + wc * 64 + n * 16 + (lane & 15);
#pragma unroll
      for (int r = 0; r < 4; ++r) {
        int row = rb + r;
        if (row < NN) PQb[(size_t)row * 256 + col] = f2bf(acc[m][n][r]);
      }
    }
  }
}

// ---------- GEMM: out[N,128] fp32 = relu(Xcat[N,512] @ WpT^T + bp) ----------
__global__ __launch_bounds__(256) void k_gemm_out(const u16* __restrict__ Xcat,
    const u16* __restrict__ WpT, const float* __restrict__ bp,
    float* __restrict__ out) {
  __shared__ u16 As[128 * 64];
  __shared__ u16 Bs[128 * 64];
  const int t = threadIdx.x;
  const int lane = t & 63, wid = t >> 6;
  const int wr = wid >> 1, wc = wid & 1;
  const int row0 = blockIdx.x * 128;
  f32x4 acc[4][4] = {};
  for (int k0 = 0; k0 < 512; k0 += 64) {
    stage_tiles<512, 512>(Xcat, WpT, row0, 0, k0, As, Bs, t);
    __syncthreads();
#pragma unroll
    for (int kk = 0; kk < 64; kk += 32) {
      bf16x8 af[4], bg[4];
#pragma unroll
      for (int m = 0; m < 4; ++m) af[m] = ld_frag(As, wr * 64 + m * 16, kk, lane);
#pragma unroll
      for (int n = 0; n < 4; ++n) bg[n] = ld_frag(Bs, wc * 64 + n * 16, kk, lane);
#pragma unroll
      for (int m = 0; m < 4; ++m)
#pragma unroll
        for (int n = 0; n < 4; ++n)
          acc[m][n] = __builtin_amdgcn_mfma_f32_16x16x32_bf16(af[m], bg[n], acc[m][n], 0, 0, 0);
    }
    __syncthreads();
  }
#pragma unroll
  for (int m = 0; m < 4; ++m) {
    int rb = row0 + wr * 64 + m * 16 + ((lane >> 4) << 2);
#pragma unroll
    for (int n = 0; n < 4; ++n) {
      int col = wc * 64 + n * 16 + (lane & 15);
      float bias = bp[col];
#pragma unroll
      for (int r = 0; r < 4; ++r) {
        int row = rb + r;
        if (row < NN) out[(size_t)row * 128 + col] = fmaxf(acc[m][n][r] + bias, 0.f);
      }
    }
  }
}

// ---------- CSR build ----------
__global__ void k_hist(const int* __restrict__ ei, int* __restrict__ cnt) {
  int e = blockIdx.x * 256 + threadIdx.x;
  if (e < EE) atomicAdd(&cnt[ei[EE + e]], 1);
}

__global__ void k_blocksum(const int* __restrict__ cnt, int* __restrict__ bsum) {
  __shared__ int sdata[256];
  int i = blockIdx.x * 256 + threadIdx.x;
  sdata[threadIdx.x] = (i < NN) ? cnt[i] : 0;
  __syncthreads();
  for (int s = 128; s > 0; s >>= 1) {
    if (threadIdx.x < s) sdata[threadIdx.x] += sdata[threadIdx.x + s];
    __syncthreads();
  }
  if (threadIdx.x == 0) bsum[blockIdx.x] = sdata[0];
}

__global__ void k_scanbsum(int* bsum, int nb) {  // single block, nb <= 256
  __shared__ int sd[256];
  int t = threadIdx.x;
  int v = (t < nb) ? bsum[t] : 0;
  sd[t] = v;
  __syncthreads();
  for (int s = 1; s < 256; s <<= 1) {
    int tv = (t >= s) ? sd[t - s] : 0;
    __syncthreads();
    sd[t] += tv;
    __syncthreads();
  }
  if (t < nb) bsum[t] = sd[t] - v;  // exclusive
}

__global__ void k_rowptr(const int* __restrict__ cnt, const int* __restrict__ bsum,
                         int* __restrict__ row_ptr, int* __restrict__ cursor) {
  __shared__ int sdata[256];
  int i = blockIdx.x * 256 + threadIdx.x;
  int v = (i < NN) ? cnt[i] : 0;
  sdata[threadIdx.x] = v;
  __syncthreads();
  for (int s = 1; s < 256; s <<= 1) {
    int tval = (threadIdx.x >= s) ? sdata[threadIdx.x - s] : 0;
    __syncthreads();
    sdata[threadIdx.x] += tval;
    __syncthreads();
  }
  int excl = sdata[threadIdx.x] - v + bsum[blockIdx.x];
  if (i < NN) { row_ptr[i] = excl; cursor[i] = excl; }
  if (i == NN - 1) row_ptr[NN] = excl + v;
}

__global__ void k_fill(const int* __restrict__ ei, int* __restrict__ cursor,
                       int* __restrict__ csr_src) {
  int e = blockIdx.x * 256 + threadIdx.x;
  if (e < EE) {
    int d = ei[EE + e];
    int pos = atomicAdd(&cursor[d], 1);
    csr_src[pos] = ei[e];
  }
}

// ---------- aggregation: one wave per node, writes bf16 into Xcat[:,128:512] ----------
__global__ __launch_bounds__(256) void k_aggr(const u16* __restrict__ PQb,
    const float* __restrict__ pre_b, const int* __restrict__ row_ptr,
    const int* __restrict__ csr_src, u16* __restrict__ Xcat) {
  int wid = (blockIdx.x * 256 + threadIdx.x) >> 6;
  int lane = threadIdx.x & 63;
  if (wid >= NN) return;
  int r0 = row_ptr[wid], r1 = row_ptr[wid + 1];
  int c = lane * 2;
  float sx = 0.f, sy = 0.f, mxx = -FLT_MAX, mxy = -FLT_MAX;
  for (int i = r0; i < r1; i++) {
    int s = csr_src[i];
    u32 q = *(const u32*)(PQb + (size_t)s * 256 + 128 + c);
    float qx = bf2f((u16)(q & 0xffffu));
    float qy = bf2f((u16)(q >> 16));
    sx += qx; sy += qy;
    mxx = fmaxf(mxx, qx); mxy = fmaxf(mxy, qy);
  }
  u32 pu = *(const u32*)(PQb + (size_t)wid * 256 + c);
  float2 b = *(const float2*)(pre_b + c);
  float px = bf2f((u16)(pu & 0xffffu)) + b.x;
  float py = bf2f((u16)(pu >> 16)) + b.y;
  int deg = r1 - r0;
  float vm_x = 0.f, vm_y = 0.f, vx_x = 0.f, vx_y = 0.f, vs_x = 0.f, vs_y = 0.f;
  if (deg > 0) {
    float inv = 1.0f / (float)deg;
    vm_x = px + sx * inv;          vm_y = py + sy * inv;
    vx_x = px + mxx;               vx_y = py + mxy;
    vs_x = (float)deg * px + sx;   vs_y = (float)deg * py + sy;
  }
  u16* arow = Xcat + (size_t)wid * 512 + 128;
  *(u32*)(arow + c)       = (u32)f2bf(vm_x) | ((u32)f2bf(vm_y) << 16);
  *(u32*)(arow + 128 + c) = (u32)f2bf(vx_x) | ((u32)f2bf(vx_y) << 16);
  *(u32*)(arow + 256 + c) = (u32)f2bf(vs_x) | ((u32)f2bf(vs_y) << 16);
}

extern "C" void kernel_launch(void* const* d_in, const int* in_sizes, int n_in,
                              void* d_out, int out_size, void* d_ws, size_t ws_size,
                              hipStream_t stream) {
  const float* x      = (const float*)d_in[0];
  const int*   ei     = (const int*)d_in[1];   // [0..E)=src, [E..2E)=dst
  const float* pre_W  = (const float*)d_in[2];
  const float* pre_b  = (const float*)d_in[3];
  const float* post_W = (const float*)d_in[4];
  const float* post_b = (const float*)d_in[5];
  const float* lin_W  = (const float*)d_in[6];
  const float* lin_b  = (const float*)d_in[7];
  float* out = (float*)d_out;

  char* ws = (char*)d_ws;
  size_t off = 0;
  auto alloc = [&](size_t bytes) { size_t o = off; off = (off + bytes + 511) & ~(size_t)511; return o; };
  u16*   Xcat    = (u16*)(ws + alloc((size_t)NN * 512 * 2));
  u16*   PQb     = (u16*)(ws + alloc((size_t)NN * 256 * 2));
  u16*   WpT     = (u16*)(ws + alloc(128 * 512 * 2));
  u16*   WpqT    = (u16*)(ws + alloc(256 * 128 * 2));
  float* bp      = (float*)(ws + alloc(128 * 4));
  int*   cnt     = (int*)(ws + alloc((size_t)NN * 4));
  int*   row_ptr = (int*)(ws + alloc((size_t)(NN + 1) * 4));
  int*   cursor  = (int*)(ws + alloc((size_t)NN * 4));
  int*   bsum    = (int*)(ws + alloc(256 * 4));
  int*   csr_src = (int*)(ws + alloc((size_t)EE * 4));
  (void)ws_size; (void)in_sizes; (void)n_in; (void)out_size;

  const int NB_N = (NN + 255) / 256;       // 196
  const int NB_E = (EE + 255) / 256;       // 3125
  const int NB_M = (NN + 127) / 128;       // 391

  hipMemsetAsync(cnt, 0, (size_t)NN * 4, stream);
  k_prep<<<(512 * 128 + 256 * 128 + 128 + 255) / 256, 256, 0, stream>>>(
      post_W, post_b, lin_W, lin_b, pre_W, WpT, WpqT, bp);
  k_convert_x<<<(NN * 16 + 255) / 256, 256, 0, stream>>>(x, Xcat);
  k_hist<<<NB_E, 256, 0, stream>>>(ei, cnt);
  k_gemm_pq<<<dim3(NB_M, 2), 256, 0, stream>>>(Xcat, WpqT, PQb);
  k_blocksum<<<NB_N, 256, 0, stream>>>(cnt, bsum);
  k_scanbsum<<<1, 256, 0, stream>>>(bsum, NB_N);
  k_rowptr<<<NB_N, 256, 0, stream>>>(cnt, bsum, row_ptr, cursor);
  k_fill<<<NB_E, 256, 0, stream>>>(ei, cursor, csr_src);
  k_aggr<<<(NN * 64 + 255) / 256, 256, 0, stream>>>(PQb, pre_b, row_ptr, csr_src, Xcat);
  k_gemm_out<<<NB_M, 256, 0, stream>>>(Xcat, WpT, bp, out);
}

// Round 4
// 195.279 us; speedup vs baseline: 1.9117x; 1.2472x over previous
//
#include <hip/hip_runtime.h>
#include <float.h>

#define NN 50000
#define EE 800000

typedef __attribute__((ext_vector_type(8))) short bf16x8;
typedef __attribute__((ext_vector_type(4))) float f32x4;
typedef unsigned short u16;
typedef unsigned int u32;

__device__ __forceinline__ u16 f2bf(float f) {
  u32 u = __builtin_bit_cast(u32, f);
  u32 r = (u + 0x7fffu + ((u >> 16) & 1u)) >> 16;
  return (u16)r;
}
__device__ __forceinline__ float bf2f(u16 h) {
  u32 u = ((u32)h) << 16;
  return __builtin_bit_cast(float, u);
}
__device__ __forceinline__ float bflo(u32 q) { return __builtin_bit_cast(float, q << 16); }
__device__ __forceinline__ float bfhi(u32 q) { return __builtin_bit_cast(float, q & 0xffff0000u); }

// ---------- prep: WpT[128][512] bf16 = (post_W @ lin_W)^T ; WpqT[256][128] bf16 = preW^T-reorg ; bp fp32 ----------
__global__ __launch_bounds__(256) void k_prep(const float* __restrict__ post_W,
    const float* __restrict__ post_b, const float* __restrict__ lin_W,
    const float* __restrict__ lin_b, const float* __restrict__ pre_W,
    u16* __restrict__ WpT, u16* __restrict__ WpqT, float* __restrict__ bp) {
  int idx = blockIdx.x * 256 + threadIdx.x;
  if (idx < 512 * 128) {
    int i = idx >> 7, j = idx & 127;
    float s = 0.f;
#pragma unroll 8
    for (int c = 0; c < 128; c++) s += post_W[i * 128 + c] * lin_W[c * 128 + j];
    WpT[j * 512 + i] = f2bf(s);
  } else if (idx < 512 * 128 + 256 * 128) {
    int u = idx - 512 * 128;
    int j = u >> 7, k = u & 127;
    float v = (j < 128) ? pre_W[k * 128 + j] : pre_W[(128 + k) * 128 + (j - 128)];
    WpqT[j * 128 + k] = f2bf(v);
  } else if (idx < 512 * 128 + 256 * 128 + 128) {
    int j = idx - (512 * 128 + 256 * 128);
    float s = lin_b[j];
    for (int c = 0; c < 128; c++) s += post_b[c] * lin_W[c * 128 + j];
    bp[j] = s;
  }
}

// ---------- convert x -> bf16 into Xcat[:, 0:128] (Xcat is [NN][512]) ----------
__global__ __launch_bounds__(256) void k_convert_x(const float* __restrict__ x,
                                                   u16* __restrict__ Xcat) {
  int tid = blockIdx.x * 256 + threadIdx.x;
  if (tid >= NN * 16) return;
  int row = tid >> 4;
  int col = (tid & 15) << 3;
  const float4 v0 = *(const float4*)(x + (size_t)row * 128 + col);
  const float4 v1 = *(const float4*)(x + (size_t)row * 128 + col + 4);
  u16 tmp[8] = {f2bf(v0.x), f2bf(v0.y), f2bf(v0.z), f2bf(v0.w),
                f2bf(v1.x), f2bf(v1.y), f2bf(v1.z), f2bf(v1.w)};
  *(bf16x8*)(Xcat + (size_t)row * 512 + col) = *(bf16x8*)tmp;
}

// ---------- MFMA GEMM helpers: K-major swizzled LDS tiles [128 rows][64 k] ----------
template <int KTOT, int LDA>
__device__ __forceinline__ void stage_tiles(const u16* __restrict__ A,
    const u16* __restrict__ BT, int row0, int n0, int k0,
    u16* __restrict__ As, u16* __restrict__ Bs, int t) {
#pragma unroll
  for (int it = 0; it < 4; ++it) {
    int c = t + it * 256;
    int row = c >> 3, ch = c & 7;
    int gr = row0 + row;
    bf16x8 v = {};
    if (gr < NN) v = *(const bf16x8*)(A + (size_t)gr * LDA + k0 + (ch << 3));
    *(bf16x8*)(As + row * 64 + ((ch ^ (row & 7)) << 3)) = v;
  }
#pragma unroll
  for (int it = 0; it < 4; ++it) {
    int c = t + it * 256;
    int n = c >> 3, ch = c & 7;
    bf16x8 v = *(const bf16x8*)(BT + (size_t)(n0 + n) * KTOT + k0 + (ch << 3));
    *(bf16x8*)(Bs + n * 64 + ((ch ^ (n & 7)) << 3)) = v;
  }
}

__device__ __forceinline__ bf16x8 ld_frag(const u16* __restrict__ S, int rowbase,
                                          int kk, int lane) {
  int r = rowbase + (lane & 15);
  int chunk = (kk >> 3) + (lane >> 4);
  int sw = chunk ^ (r & 7);
  return *(const bf16x8*)(S + r * 64 + (sw << 3));
}

// ---------- GEMM: PQb[N,256] bf16 = Xcat[:,0:128] @ WpqT^T ----------
__global__ __launch_bounds__(256) void k_gemm_pq(const u16* __restrict__ Xcat,
    const u16* __restrict__ WpqT, u16* __restrict__ PQb) {
  __shared__ u16 As[128 * 64];
  __shared__ u16 Bs[128 * 64];
  const int t = threadIdx.x;
  const int lane = t & 63, wid = t >> 6;
  const int wr = wid >> 1, wc = wid & 1;
  const int row0 = blockIdx.x * 128;
  const int n0 = blockIdx.y * 128;
  f32x4 acc[4][4] = {};
  for (int k0 = 0; k0 < 128; k0 += 64) {
    stage_tiles<128, 512>(Xcat, WpqT, row0, n0, k0, As, Bs, t);
    __syncthreads();
#pragma unroll
    for (int kk = 0; kk < 64; kk += 32) {
      bf16x8 af[4], bg[4];
#pragma unroll
      for (int m = 0; m < 4; ++m) af[m] = ld_frag(As, wr * 64 + m * 16, kk, lane);
#pragma unroll
      for (int n = 0; n < 4; ++n) bg[n] = ld_frag(Bs, wc * 64 + n * 16, kk, lane);
#pragma unroll
      for (int m = 0; m < 4; ++m)
#pragma unroll
        for (int n = 0; n < 4; ++n)
          acc[m][n] = __builtin_amdgcn_mfma_f32_16x16x32_bf16(af[m], bg[n], acc[m][n], 0, 0, 0);
    }
    __syncthreads();
  }
#pragma unroll
  for (int m = 0; m < 4; ++m) {
    int rb = row0 + wr * 64 + m * 16 + ((lane >> 4) << 2);
#pragma unroll
    for (int n = 0; n < 4; ++n) {
      int col = n0 + wc * 64 + n * 16 + (lane & 15);
#pragma unroll
      for (int r = 0; r < 4; ++r) {
        int row = rb + r;
        if (row < NN) PQb[(size_t)row * 256 + col] = f2bf(acc[m][n][r]);
      }
    }
  }
}

// ---------- GEMM: out[N,128] fp32 = relu(Xcat[N,512] @ WpT^T + bp) ----------
__global__ __launch_bounds__(256) void k_gemm_out(const u16* __restrict__ Xcat,
    const u16* __restrict__ WpT, const float* __restrict__ bp,
    float* __restrict__ out) {
  __shared__ u16 As[128 * 64];
  __shared__ u16 Bs[128 * 64];
  const int t = threadIdx.x;
  const int lane = t & 63, wid = t >> 6;
  const int wr = wid >> 1, wc = wid & 1;
  const int row0 = blockIdx.x * 128;
  f32x4 acc[4][4] = {};
  for (int k0 = 0; k0 < 512; k0 += 64) {
    stage_tiles<512, 512>(Xcat, WpT, row0, 0, k0, As, Bs, t);
    __syncthreads();
#pragma unroll
    for (int kk = 0; kk < 64; kk += 32) {
      bf16x8 af[4], bg[4];
#pragma unroll
      for (int m = 0; m < 4; ++m) af[m] = ld_frag(As, wr * 64 + m * 16, kk, lane);
#pragma unroll
      for (int n = 0; n < 4; ++n) bg[n] = ld_frag(Bs, wc * 64 + n * 16, kk, lane);
#pragma unroll
      for (int m = 0; m < 4; ++m)
#pragma unroll
        for (int n = 0; n < 4; ++n)
          acc[m][n] = __builtin_amdgcn_mfma_f32_16x16x32_bf16(af[m], bg[n], acc[m][n], 0, 0, 0);
    }
    __syncthreads();
  }
#pragma unroll
  for (int m = 0; m < 4; ++m) {
    int rb = row0 + wr * 64 + m * 16 + ((lane >> 4) << 2);
#pragma unroll
    for (int n = 0; n < 4; ++n) {
      int col = wc * 64 + n * 16 + (lane & 15);
      float bias = bp[col];
#pragma unroll
      for (int r = 0; r < 4; ++r) {
        int row = rb + r;
        if (row < NN) out[(size_t)row * 128 + col] = fmaxf(acc[m][n][r] + bias, 0.f);
      }
    }
  }
}

// ---------- CSR build ----------
__global__ void k_hist(const int* __restrict__ ei, int* __restrict__ cnt) {
  int e = blockIdx.x * 256 + threadIdx.x;
  if (e < EE) atomicAdd(&cnt[ei[EE + e]], 1);
}

__global__ void k_blocksum(const int* __restrict__ cnt, int* __restrict__ bsum) {
  __shared__ int sdata[256];
  int i = blockIdx.x * 256 + threadIdx.x;
  sdata[threadIdx.x] = (i < NN) ? cnt[i] : 0;
  __syncthreads();
  for (int s = 128; s > 0; s >>= 1) {
    if (threadIdx.x < s) sdata[threadIdx.x] += sdata[threadIdx.x + s];
    __syncthreads();
  }
  if (threadIdx.x == 0) bsum[blockIdx.x] = sdata[0];
}

__global__ void k_scanbsum(int* bsum, int nb) {  // single block, nb <= 256
  __shared__ int sd[256];
  int t = threadIdx.x;
  int v = (t < nb) ? bsum[t] : 0;
  sd[t] = v;
  __syncthreads();
  for (int s = 1; s < 256; s <<= 1) {
    int tv = (t >= s) ? sd[t - s] : 0;
    __syncthreads();
    sd[t] += tv;
    __syncthreads();
  }
  if (t < nb) bsum[t] = sd[t] - v;  // exclusive
}

__global__ void k_rowptr(const int* __restrict__ cnt, const int* __restrict__ bsum,
                         int* __restrict__ row_ptr, int* __restrict__ cursor) {
  __shared__ int sdata[256];
  int i = blockIdx.x * 256 + threadIdx.x;
  int v = (i < NN) ? cnt[i] : 0;
  sdata[threadIdx.x] = v;
  __syncthreads();
  for (int s = 1; s < 256; s <<= 1) {
    int tval = (threadIdx.x >= s) ? sdata[threadIdx.x - s] : 0;
    __syncthreads();
    sdata[threadIdx.x] += tval;
    __syncthreads();
  }
  int excl = sdata[threadIdx.x] - v + bsum[blockIdx.x];
  if (i < NN) { row_ptr[i] = excl; cursor[i] = excl; }
  if (i == NN - 1) row_ptr[NN] = excl + v;
}

__global__ void k_fill(const int* __restrict__ ei, int* __restrict__ cursor,
                       int* __restrict__ csr_src) {
  int e = blockIdx.x * 256 + threadIdx.x;
  if (e < EE) {
    int d = ei[EE + e];
    int pos = atomicAdd(&cursor[d], 1);
    csr_src[pos] = ei[e];
  }
}

// ---------- aggregation: one wave per node; unmasked 8-batches + 4-batch + serial tail ----------
__global__ __launch_bounds__(256) void k_aggr(const u16* __restrict__ PQb,
    const float* __restrict__ pre_b, const int* __restrict__ row_ptr,
    const int* __restrict__ csr_src, u16* __restrict__ Xcat) {
  int wid = (blockIdx.x * 256 + threadIdx.x) >> 6;
  int lane = threadIdx.x & 63;
  if (wid >= NN) return;
  int r0 = row_ptr[wid], r1 = row_ptr[wid + 1];
  int c = lane * 2;
  const u16* Qbase = PQb + 128 + c;  // row s -> Qbase + s*256
  float sx = 0.f, sy = 0.f, mxx = -FLT_MAX, mxy = -FLT_MAX;
  int i = r0;
  // unmasked batches of 8: every load is a distinct real edge
  for (; i + 8 <= r1; i += 8) {
    int s[8];
#pragma unroll
    for (int k = 0; k < 8; ++k) s[k] = csr_src[i + k];
    u32 q[8];
#pragma unroll
    for (int k = 0; k < 8; ++k) q[k] = *(const u32*)(Qbase + (size_t)s[k] * 256);
#pragma unroll
    for (int k = 0; k < 8; ++k) {
      float qx = bflo(q[k]), qy = bfhi(q[k]);
      sx += qx; sy += qy;
      mxx = fmaxf(mxx, qx); mxy = fmaxf(mxy, qy);
    }
  }
  // one unmasked batch of 4 if at least 4 remain
  if (i + 4 <= r1) {
    int s[4];
#pragma unroll
    for (int k = 0; k < 4; ++k) s[k] = csr_src[i + k];
    u32 q[4];
#pragma unroll
    for (int k = 0; k < 4; ++k) q[k] = *(const u32*)(Qbase + (size_t)s[k] * 256);
#pragma unroll
    for (int k = 0; k < 4; ++k) {
      float qx = bflo(q[k]), qy = bfhi(q[k]);
      sx += qx; sy += qy;
      mxx = fmaxf(mxx, qx); mxy = fmaxf(mxy, qy);
    }
    i += 4;
  }
  // serial tail (<=3 iterations) — verbatim round-2 inner loop
  for (; i < r1; ++i) {
    int s = csr_src[i];
    u32 q = *(const u32*)(Qbase + (size_t)s * 256);
    float qx = bflo(q), qy = bfhi(q);
    sx += qx; sy += qy;
    mxx = fmaxf(mxx, qx); mxy = fmaxf(mxy, qy);
  }
  u32 pu = *(const u32*)(PQb + (size_t)wid * 256 + c);
  float2 b = *(const float2*)(pre_b + c);
  float px = bflo(pu) + b.x;
  float py = bfhi(pu) + b.y;
  int deg = r1 - r0;
  float vm_x = 0.f, vm_y = 0.f, vx_x = 0.f, vx_y = 0.f, vs_x = 0.f, vs_y = 0.f;
  if (deg > 0) {
    float inv = 1.0f / (float)deg;
    vm_x = px + sx * inv;          vm_y = py + sy * inv;
    vx_x = px + mxx;               vx_y = py + mxy;
    vs_x = (float)deg * px + sx;   vs_y = (float)deg * py + sy;
  }
  u16* arow = Xcat + (size_t)wid * 512 + 128;
  *(u32*)(arow + c)       = (u32)f2bf(vm_x) | ((u32)f2bf(vm_y) << 16);
  *(u32*)(arow + 128 + c) = (u32)f2bf(vx_x) | ((u32)f2bf(vx_y) << 16);
  *(u32*)(arow + 256 + c) = (u32)f2bf(vs_x) | ((u32)f2bf(vs_y) << 16);
}

extern "C" void kernel_launch(void* const* d_in, const int* in_sizes, int n_in,
                              void* d_out, int out_size, void* d_ws, size_t ws_size,
                              hipStream_t stream) {
  const float* x      = (const float*)d_in[0];
  const int*   ei     = (const int*)d_in[1];   // [0..E)=src, [E..2E)=dst
  const float* pre_W  = (const float*)d_in[2];
  const float* pre_b  = (const float*)d_in[3];
  const float* post_W = (const float*)d_in[4];
  const float* post_b = (const float*)d_in[5];
  const float* lin_W  = (const float*)d_in[6];
  const float* lin_b  = (const float*)d_in[7];
  float* out = (float*)d_out;

  char* ws = (char*)d_ws;
  size_t off = 0;
  auto alloc = [&](size_t bytes) { size_t o = off; off = (off + bytes + 511) & ~(size_t)511; return o; };
  u16*   Xcat    = (u16*)(ws + alloc((size_t)NN * 512 * 2));
  u16*   PQb     = (u16*)(ws + alloc((size_t)NN * 256 * 2));
  u16*   WpT     = (u16*)(ws + alloc(128 * 512 * 2));
  u16*   WpqT    = (u16*)(ws + alloc(256 * 128 * 2));
  float* bp      = (float*)(ws + alloc(128 * 4));
  int*   cnt     = (int*)(ws + alloc((size_t)NN * 4));
  int*   row_ptr = (int*)(ws + alloc((size_t)(NN + 1) * 4));
  int*   cursor  = (int*)(ws + alloc((size_t)NN * 4));
  int*   bsum    = (int*)(ws + alloc(256 * 4));
  int*   csr_src = (int*)(ws + alloc((size_t)EE * 4));
  (void)ws_size; (void)in_sizes; (void)n_in; (void)out_size;

  const int NB_N = (NN + 255) / 256;       // 196
  const int NB_E = (EE + 255) / 256;       // 3125
  const int NB_M = (NN + 127) / 128;       // 391

  hipMemsetAsync(cnt, 0, (size_t)NN * 4, stream);
  k_prep<<<(512 * 128 + 256 * 128 + 128 + 255) / 256, 256, 0, stream>>>(
      post_W, post_b, lin_W, lin_b, pre_W, WpT, WpqT, bp);
  k_convert_x<<<(NN * 16 + 255) / 256, 256, 0, stream>>>(x, Xcat);
  k_hist<<<NB_E, 256, 0, stream>>>(ei, cnt);
  k_gemm_pq<<<dim3(NB_M, 2), 256, 0, stream>>>(Xcat, WpqT, PQb);
  k_blocksum<<<NB_N, 256, 0, stream>>>(cnt, bsum);
  k_scanbsum<<<1, 256, 0, stream>>>(bsum, NB_N);
  k_rowptr<<<NB_N, 256, 0, stream>>>(cnt, bsum, row_ptr, cursor);
  k_fill<<<NB_E, 256, 0, stream>>>(ei, cursor, csr_src);
  k_aggr<<<(NN * 64 + 255) / 256, 256, 0, stream>>>(PQb, pre_b, row_ptr, csr_src, Xcat);
  k_gemm_out<<<NB_M, 256, 0, stream>>>(Xcat, WpT, bp, out);
}

// Round 5
// 163.200 us; speedup vs baseline: 2.2874x; 1.1966x over previous
//
#include <hip/hip_runtime.h>
#include <float.h>

#define NN 50000
#define EE 800000
#define NBKT 196   // ceil(NN/256) node buckets
#define T1 4096    // edges per k_bucket tile
#define CAP2 8192  // max edges per bucket in k_sortbucket fast path (E[count]=4081, sigma~64)

typedef __attribute__((ext_vector_type(8))) short bf16x8;
typedef __attribute__((ext_vector_type(4))) float f32x4;
typedef unsigned short u16;
typedef unsigned int u32;

__device__ __forceinline__ u16 f2bf(float f) {
  u32 u = __builtin_bit_cast(u32, f);
  u32 r = (u + 0x7fffu + ((u >> 16) & 1u)) >> 16;
  return (u16)r;
}
__device__ __forceinline__ float bflo(u32 q) { return __builtin_bit_cast(float, q << 16); }
__device__ __forceinline__ float bfhi(u32 q) { return __builtin_bit_cast(float, q & 0xffff0000u); }

// ---------- prep: WpT[128][512] bf16 = (post_W @ lin_W)^T ; WpqT[256][128] bf16 = preW^T-reorg ; bp fp32 ----------
__global__ __launch_bounds__(256) void k_prep(const float* __restrict__ post_W,
    const float* __restrict__ post_b, const float* __restrict__ lin_W,
    const float* __restrict__ lin_b, const float* __restrict__ pre_W,
    u16* __restrict__ WpT, u16* __restrict__ WpqT, float* __restrict__ bp) {
  int idx = blockIdx.x * 256 + threadIdx.x;
  if (idx < 512 * 128) {
    int i = idx >> 7, j = idx & 127;
    float s = 0.f;
#pragma unroll 8
    for (int c = 0; c < 128; c++) s += post_W[i * 128 + c] * lin_W[c * 128 + j];
    WpT[j * 512 + i] = f2bf(s);
  } else if (idx < 512 * 128 + 256 * 128) {
    int u = idx - 512 * 128;
    int j = u >> 7, k = u & 127;
    float v = (j < 128) ? pre_W[k * 128 + j] : pre_W[(128 + k) * 128 + (j - 128)];
    WpqT[j * 128 + k] = f2bf(v);
  } else if (idx < 512 * 128 + 256 * 128 + 128) {
    int j = idx - (512 * 128 + 256 * 128);
    float s = lin_b[j];
    for (int c = 0; c < 128; c++) s += post_b[c] * lin_W[c * 128 + j];
    bp[j] = s;
  }
}

// ---------- convert x -> bf16 into Xcat[:, 0:128] (Xcat is [NN][512]) ----------
__global__ __launch_bounds__(256) void k_convert_x(const float* __restrict__ x,
                                                   u16* __restrict__ Xcat) {
  int tid = blockIdx.x * 256 + threadIdx.x;
  if (tid >= NN * 16) return;
  int row = tid >> 4;
  int col = (tid & 15) << 3;
  const float4 v0 = *(const float4*)(x + (size_t)row * 128 + col);
  const float4 v1 = *(const float4*)(x + (size_t)row * 128 + col + 4);
  u16 tmp[8] = {f2bf(v0.x), f2bf(v0.y), f2bf(v0.z), f2bf(v0.w),
                f2bf(v1.x), f2bf(v1.y), f2bf(v1.z), f2bf(v1.w)};
  *(bf16x8*)(Xcat + (size_t)row * 512 + col) = *(bf16x8*)tmp;
}

// ---------- MFMA GEMM helpers: K-major swizzled LDS tiles [128 rows][64 k] ----------
template <int KTOT, int LDA>
__device__ __forceinline__ void stage_tiles(const u16* __restrict__ A,
    const u16* __restrict__ BT, int row0, int n0, int k0,
    u16* __restrict__ As, u16* __restrict__ Bs, int t) {
#pragma unroll
  for (int it = 0; it < 4; ++it) {
    int c = t + it * 256;
    int row = c >> 3, ch = c & 7;
    int gr = row0 + row;
    bf16x8 v = {};
    if (gr < NN) v = *(const bf16x8*)(A + (size_t)gr * LDA + k0 + (ch << 3));
    *(bf16x8*)(As + row * 64 + ((ch ^ (row & 7)) << 3)) = v;
  }
#pragma unroll
  for (int it = 0; it < 4; ++it) {
    int c = t + it * 256;
    int n = c >> 3, ch = c & 7;
    bf16x8 v = *(const bf16x8*)(BT + (size_t)(n0 + n) * KTOT + k0 + (ch << 3));
    *(bf16x8*)(Bs + n * 64 + ((ch ^ (n & 7)) << 3)) = v;
  }
}

__device__ __forceinline__ bf16x8 ld_frag(const u16* __restrict__ S, int rowbase,
                                          int kk, int lane) {
  int r = rowbase + (lane & 15);
  int chunk = (kk >> 3) + (lane >> 4);
  int sw = chunk ^ (r & 7);
  return *(const bf16x8*)(S + r * 64 + (sw << 3));
}

// ---------- GEMM: PQb[N,256] bf16 = Xcat[:,0:128] @ WpqT^T ----------
__global__ __launch_bounds__(256) void k_gemm_pq(const u16* __restrict__ Xcat,
    const u16* __restrict__ WpqT, u16* __restrict__ PQb) {
  __shared__ u16 As[128 * 64];
  __shared__ u16 Bs[128 * 64];
  const int t = threadIdx.x;
  const int lane = t & 63, wid = t >> 6;
  const int wr = wid >> 1, wc = wid & 1;
  const int row0 = blockIdx.x * 128;
  const int n0 = blockIdx.y * 128;
  f32x4 acc[4][4] = {};
  for (int k0 = 0; k0 < 128; k0 += 64) {
    stage_tiles<128, 512>(Xcat, WpqT, row0, n0, k0, As, Bs, t);
    __syncthreads();
#pragma unroll
    for (int kk = 0; kk < 64; kk += 32) {
      bf16x8 af[4], bg[4];
#pragma unroll
      for (int m = 0; m < 4; ++m) af[m] = ld_frag(As, wr * 64 + m * 16, kk, lane);
#pragma unroll
      for (int n = 0; n < 4; ++n) bg[n] = ld_frag(Bs, wc * 64 + n * 16, kk, lane);
#pragma unroll
      for (int m = 0; m < 4; ++m)
#pragma unroll
        for (int n = 0; n < 4; ++n)
          acc[m][n] = __builtin_amdgcn_mfma_f32_16x16x32_bf16(af[m], bg[n], acc[m][n], 0, 0, 0);
    }
    __syncthreads();
  }
#pragma unroll
  for (int m = 0; m < 4; ++m) {
    int rb = row0 + wr * 64 + m * 16 + ((lane >> 4) << 2);
#pragma unroll
    for (int n = 0; n < 4; ++n) {
      int col = n0 + wc * 64 + n * 16 + (lane & 15);
#pragma unroll
      for (int r = 0; r < 4; ++r) {
        int row = rb + r;
        if (row < NN) PQb[(size_t)row * 256 + col] = f2bf(acc[m][n][r]);
      }
    }
  }
}

// ---------- GEMM: out[N,128] fp32 = relu(Xcat[N,512] @ WpT^T + bp) ----------
__global__ __launch_bounds__(256) void k_gemm_out(const u16* __restrict__ Xcat,
    const u16* __restrict__ WpT, const float* __restrict__ bp,
    float* __restrict__ out) {
  __shared__ u16 As[128 * 64];
  __shared__ u16 Bs[128 * 64];
  const int t = threadIdx.x;
  const int lane = t & 63, wid = t >> 6;
  const int wr = wid >> 1, wc = wid & 1;
  const int row0 = blockIdx.x * 128;
  f32x4 acc[4][4] = {};
  for (int k0 = 0; k0 < 512; k0 += 64) {
    stage_tiles<512, 512>(Xcat, WpT, row0, 0, k0, As, Bs, t);
    __syncthreads();
#pragma unroll
    for (int kk = 0; kk < 64; kk += 32) {
      bf16x8 af[4], bg[4];
#pragma unroll
      for (int m = 0; m < 4; ++m) af[m] = ld_frag(As, wr * 64 + m * 16, kk, lane);
#pragma unroll
      for (int n = 0; n < 4; ++n) bg[n] = ld_frag(Bs, wc * 64 + n * 16, kk, lane);
#pragma unroll
      for (int m = 0; m < 4; ++m)
#pragma unroll
        for (int n = 0; n < 4; ++n)
          acc[m][n] = __builtin_amdgcn_mfma_f32_16x16x32_bf16(af[m], bg[n], acc[m][n], 0, 0, 0);
    }
    __syncthreads();
  }
#pragma unroll
  for (int m = 0; m < 4; ++m) {
    int rb = row0 + wr * 64 + m * 16 + ((lane >> 4) << 2);
#pragma unroll
    for (int n = 0; n < 4; ++n) {
      int col = wc * 64 + n * 16 + (lane & 15);
      float bias = bp[col];
#pragma unroll
      for (int r = 0; r < 4; ++r) {
        int row = rb + r;
        if (row < NN) out[(size_t)row * 128 + col] = fmaxf(acc[m][n][r] + bias, 0.f);
      }
    }
  }
}

// ---------- CSR build: hist + scan ----------
__global__ void k_hist(const int* __restrict__ ei, int* __restrict__ cnt) {
  int e = blockIdx.x * 256 + threadIdx.x;
  if (e < EE) atomicAdd(&cnt[ei[EE + e]], 1);
}

__global__ void k_blocksum(const int* __restrict__ cnt, int* __restrict__ bsum) {
  __shared__ int sdata[256];
  int i = blockIdx.x * 256 + threadIdx.x;
  sdata[threadIdx.x] = (i < NN) ? cnt[i] : 0;
  __syncthreads();
  for (int s = 128; s > 0; s >>= 1) {
    if (threadIdx.x < s) sdata[threadIdx.x] += sdata[threadIdx.x + s];
    __syncthreads();
  }
  if (threadIdx.x == 0) bsum[blockIdx.x] = sdata[0];
}

__global__ void k_scanbsum(int* bsum, int nb) {  // single block, nb <= 256
  __shared__ int sd[256];
  int t = threadIdx.x;
  int v = (t < nb) ? bsum[t] : 0;
  sd[t] = v;
  __syncthreads();
  for (int s = 1; s < 256; s <<= 1) {
    int tv = (t >= s) ? sd[t - s] : 0;
    __syncthreads();
    sd[t] += tv;
    __syncthreads();
  }
  if (t < nb) bsum[t] = sd[t] - v;  // exclusive
}

__global__ void k_rowptr(const int* __restrict__ cnt, const int* __restrict__ bsum,
                         int* __restrict__ row_ptr, int* __restrict__ cursor) {
  __shared__ int sdata[256];
  int i = blockIdx.x * 256 + threadIdx.x;
  int v = (i < NN) ? cnt[i] : 0;
  sdata[threadIdx.x] = v;
  __syncthreads();
  for (int s = 1; s < 256; s <<= 1) {
    int tval = (threadIdx.x >= s) ? sdata[threadIdx.x - s] : 0;
    __syncthreads();
    sdata[threadIdx.x] += tval;
    __syncthreads();
  }
  int excl = sdata[threadIdx.x] - v + bsum[blockIdx.x];
  if (i < NN) { row_ptr[i] = excl; cursor[i] = excl; }
  if (i == NN - 1) row_ptr[NN] = excl + v;
}

__global__ void k_bcursor(const int* __restrict__ row_ptr, int* __restrict__ bucket_cursor) {
  int i = threadIdx.x;  // single block of 256
  if (i < NBKT) bucket_cursor[i] = row_ptr[i * 256];
}

// ---------- pass 1: tile-sorted bucket scatter of packed (dst<<16|src) into ebuf ----------
__global__ __launch_bounds__(256) void k_bucket(const int* __restrict__ ei,
    int* __restrict__ bucket_cursor, u32* __restrict__ ebuf) {
  __shared__ u32 tilebuf[T1];
  __shared__ u32 gpos[T1];
  __shared__ int hist[256], scan_[256], runbase[256], ctr[256];
  const int t = threadIdx.x;
  const int e0 = blockIdx.x * T1;
  const int ecount = min(T1, EE - e0);
  hist[t] = 0;
  __syncthreads();
  u32 myp[16];
  int myb[16];
#pragma unroll
  for (int k = 0; k < 16; ++k) {
    int idx = t + k * 256;
    myp[k] = 0; myb[k] = 0;
    if (idx < ecount) {
      int e = e0 + idx;
      int s = ei[e], d = ei[EE + e];
      myp[k] = ((u32)d << 16) | (u32)s;
      int b = d >> 8;
      myb[k] = b;
      atomicAdd(&hist[b], 1);
    }
  }
  __syncthreads();
  int v = hist[t];
  scan_[t] = v;
  __syncthreads();
  for (int s_ = 1; s_ < 256; s_ <<= 1) {
    int tv = (t >= s_) ? scan_[t - s_] : 0;
    __syncthreads();
    scan_[t] += tv;
    __syncthreads();
  }
  int excl = scan_[t] - v;
  __syncthreads();
  scan_[t] = excl;
  ctr[t] = 0;
  if (v > 0) runbase[t] = atomicAdd(&bucket_cursor[t], v);  // only t<NBKT can have v>0
  __syncthreads();
#pragma unroll
  for (int k = 0; k < 16; ++k) {
    int idx = t + k * 256;
    if (idx < ecount) {
      int b = myb[k];
      int l = atomicAdd(&ctr[b], 1);
      int slot = scan_[b] + l;
      tilebuf[slot] = myp[k];
      gpos[slot] = (u32)(runbase[b] + l);
    }
  }
  __syncthreads();
  for (int j = t; j < ecount; j += 256) ebuf[gpos[j]] = tilebuf[j];
}

// ---------- pass 2: per-bucket LDS counting sort -> exact per-node CSR (u16 src), coalesced out ----------
__global__ __launch_bounds__(256) void k_sortbucket(const u32* __restrict__ ebuf,
    const int* __restrict__ row_ptr, int* __restrict__ cursor, u16* __restrict__ csr_src) {
  __shared__ u32 buf[CAP2];     // 32 KB
  __shared__ u16 sorted[CAP2];  // 16 KB
  __shared__ int hist[256], scan_[256], ctr[256];
  const int b = blockIdx.x;
  const int t = threadIdx.x;
  const int n0 = b * 256;
  const int n1 = min(n0 + 256, NN);
  const int base = row_ptr[n0];
  const int end = row_ptr[n1];
  const int count = end - base;
  if (count <= CAP2) {
    for (int j = t; j < count; j += 256) buf[j] = ebuf[base + j];
    hist[t] = 0;
    __syncthreads();
    for (int j = t; j < count; j += 256) atomicAdd(&hist[(buf[j] >> 16) & 255], 1);
    __syncthreads();
    int v = hist[t];
    scan_[t] = v;
    __syncthreads();
    for (int s_ = 1; s_ < 256; s_ <<= 1) {
      int tv = (t >= s_) ? scan_[t - s_] : 0;
      __syncthreads();
      scan_[t] += tv;
      __syncthreads();
    }
    int excl = scan_[t] - v;
    __syncthreads();
    scan_[t] = excl;
    ctr[t] = 0;
    __syncthreads();
    for (int j = t; j < count; j += 256) {
      u32 p = buf[j];
      int ln = (p >> 16) & 255;
      int l = atomicAdd(&ctr[ln], 1);
      sorted[scan_[ln] + l] = (u16)(p & 0xffffu);
    }
    __syncthreads();
    for (int j = t; j < count; j += 256) csr_src[base + j] = sorted[j];
  } else {
    // safety fallback (statistically unreachable): atomic scatter via per-node cursor
    for (int j = t; j < count; j += 256) {
      u32 p = ebuf[base + j];
      int d = (int)(p >> 16);
      int pos = atomicAdd(&cursor[d], 1);
      csr_src[pos] = (u16)(p & 0xffffu);
    }
  }
}

// ---------- aggregation: one wave per node; unmasked 16/8/4-batches + serial tail ----------
__global__ __launch_bounds__(256) void k_aggr(const u16* __restrict__ PQb,
    const float* __restrict__ pre_b, const int* __restrict__ row_ptr,
    const u16* __restrict__ csr_src, u16* __restrict__ Xcat) {
  int wid = (blockIdx.x * 256 + threadIdx.x) >> 6;
  int lane = threadIdx.x & 63;
  if (wid >= NN) return;
  int r0 = row_ptr[wid], r1 = row_ptr[wid + 1];
  int c = lane * 2;
  const u16* Qbase = PQb + 128 + c;  // row s -> Qbase + s*256
  float sx = 0.f, sy = 0.f, mxx = -FLT_MAX, mxy = -FLT_MAX;
  int i = r0;
  for (; i + 16 <= r1; i += 16) {
    int s[16];
#pragma unroll
    for (int k = 0; k < 16; ++k) s[k] = csr_src[i + k];
    u32 q[16];
#pragma unroll
    for (int k = 0; k < 16; ++k) q[k] = *(const u32*)(Qbase + (size_t)s[k] * 256);
#pragma unroll
    for (int k = 0; k < 16; ++k) {
      float qx = bflo(q[k]), qy = bfhi(q[k]);
      sx += qx; sy += qy;
      mxx = fmaxf(mxx, qx); mxy = fmaxf(mxy, qy);
    }
  }
  if (i + 8 <= r1) {
    int s[8];
#pragma unroll
    for (int k = 0; k < 8; ++k) s[k] = csr_src[i + k];
    u32 q[8];
#pragma unroll
    for (int k = 0; k < 8; ++k) q[k] = *(const u32*)(Qbase + (size_t)s[k] * 256);
#pragma unroll
    for (int k = 0; k < 8; ++k) {
      float qx = bflo(q[k]), qy = bfhi(q[k]);
      sx += qx; sy += qy;
      mxx = fmaxf(mxx, qx); mxy = fmaxf(mxy, qy);
    }
    i += 8;
  }
  if (i + 4 <= r1) {
    int s[4];
#pragma unroll
    for (int k = 0; k < 4; ++k) s[k] = csr_src[i + k];
    u32 q[4];
#pragma unroll
    for (int k = 0; k < 4; ++k) q[k] = *(const u32*)(Qbase + (size_t)s[k] * 256);
#pragma unroll
    for (int k = 0; k < 4; ++k) {
      float qx = bflo(q[k]), qy = bfhi(q[k]);
      sx += qx; sy += qy;
      mxx = fmaxf(mxx, qx); mxy = fmaxf(mxy, qy);
    }
    i += 4;
  }
  for (; i < r1; ++i) {
    int s = csr_src[i];
    u32 q = *(const u32*)(Qbase + (size_t)s * 256);
    float qx = bflo(q), qy = bfhi(q);
    sx += qx; sy += qy;
    mxx = fmaxf(mxx, qx); mxy = fmaxf(mxy, qy);
  }
  u32 pu = *(const u32*)(PQb + (size_t)wid * 256 + c);
  float2 b = *(const float2*)(pre_b + c);
  float px = bflo(pu) + b.x;
  float py = bfhi(pu) + b.y;
  int deg = r1 - r0;
  float vm_x = 0.f, vm_y = 0.f, vx_x = 0.f, vx_y = 0.f, vs_x = 0.f, vs_y = 0.f;
  if (deg > 0) {
    float inv = 1.0f / (float)deg;
    vm_x = px + sx * inv;          vm_y = py + sy * inv;
    vx_x = px + mxx;               vx_y = py + mxy;
    vs_x = (float)deg * px + sx;   vs_y = (float)deg * py + sy;
  }
  u16* arow = Xcat + (size_t)wid * 512 + 128;
  *(u32*)(arow + c)       = (u32)f2bf(vm_x) | ((u32)f2bf(vm_y) << 16);
  *(u32*)(arow + 128 + c) = (u32)f2bf(vx_x) | ((u32)f2bf(vx_y) << 16);
  *(u32*)(arow + 256 + c) = (u32)f2bf(vs_x) | ((u32)f2bf(vs_y) << 16);
}

extern "C" void kernel_launch(void* const* d_in, const int* in_sizes, int n_in,
                              void* d_out, int out_size, void* d_ws, size_t ws_size,
                              hipStream_t stream) {
  const float* x      = (const float*)d_in[0];
  const int*   ei     = (const int*)d_in[1];   // [0..E)=src, [E..2E)=dst
  const float* pre_W  = (const float*)d_in[2];
  const float* pre_b  = (const float*)d_in[3];
  const float* post_W = (const float*)d_in[4];
  const float* post_b = (const float*)d_in[5];
  const float* lin_W  = (const float*)d_in[6];
  const float* lin_b  = (const float*)d_in[7];
  float* out = (float*)d_out;

  char* ws = (char*)d_ws;
  size_t off = 0;
  auto alloc = [&](size_t bytes) { size_t o = off; off = (off + bytes + 511) & ~(size_t)511; return o; };
  u16*   Xcat    = (u16*)(ws + alloc((size_t)NN * 512 * 2));
  u16*   PQb     = (u16*)(ws + alloc((size_t)NN * 256 * 2));
  u16*   WpT     = (u16*)(ws + alloc(128 * 512 * 2));
  u16*   WpqT    = (u16*)(ws + alloc(256 * 128 * 2));
  float* bp      = (float*)(ws + alloc(128 * 4));
  int*   cnt     = (int*)(ws + alloc((size_t)NN * 4));
  int*   row_ptr = (int*)(ws + alloc((size_t)(NN + 1) * 4));
  int*   cursor  = (int*)(ws + alloc((size_t)NN * 4));
  int*   bsum    = (int*)(ws + alloc(256 * 4));
  int*   bucket_cursor = (int*)(ws + alloc(256 * 4));
  u32*   ebuf    = (u32*)(ws + alloc((size_t)EE * 4));
  u16*   csr_src = (u16*)(ws + alloc((size_t)EE * 2));
  (void)ws_size; (void)in_sizes; (void)n_in; (void)out_size;

  const int NB_N = (NN + 255) / 256;       // 196
  const int NB_E = (EE + 255) / 256;       // 3125
  const int NB_M = (NN + 127) / 128;       // 391
  const int NB_T = (EE + T1 - 1) / T1;     // 196

  hipMemsetAsync(cnt, 0, (size_t)NN * 4, stream);
  k_prep<<<(512 * 128 + 256 * 128 + 128 + 255) / 256, 256, 0, stream>>>(
      post_W, post_b, lin_W, lin_b, pre_W, WpT, WpqT, bp);
  k_convert_x<<<(NN * 16 + 255) / 256, 256, 0, stream>>>(x, Xcat);
  k_hist<<<NB_E, 256, 0, stream>>>(ei, cnt);
  k_gemm_pq<<<dim3(NB_M, 2), 256, 0, stream>>>(Xcat, WpqT, PQb);
  k_blocksum<<<NB_N, 256, 0, stream>>>(cnt, bsum);
  k_scanbsum<<<1, 256, 0, stream>>>(bsum, NB_N);
  k_rowptr<<<NB_N, 256, 0, stream>>>(cnt, bsum, row_ptr, cursor);
  k_bcursor<<<1, 256, 0, stream>>>(row_ptr, bucket_cursor);
  k_bucket<<<NB_T, 256, 0, stream>>>(ei, bucket_cursor, ebuf);
  k_sortbucket<<<NBKT, 256, 0, stream>>>(ebuf, row_ptr, cursor, csr_src);
  k_aggr<<<(NN * 64 + 255) / 256, 256, 0, stream>>>(PQb, pre_b, row_ptr, csr_src, Xcat);
  k_gemm_out<<<NB_M, 256, 0, stream>>>(Xcat, WpT, bp, out);
}

// Round 6
// 126.641 us; speedup vs baseline: 2.9478x; 1.2887x over previous
//
#include <hip/hip_runtime.h>
#include <float.h>

#define NN 50000
#define EE 800000
#define NBKT 196   // ceil(NN/256) node buckets
#define T1 4096    // edges per tile
#define CAP2 8192  // max edges per bucket in k_sortbucket fast path (E[count]=4081, sigma~64)

typedef __attribute__((ext_vector_type(8))) short bf16x8;
typedef __attribute__((ext_vector_type(4))) float f32x4;
typedef unsigned short u16;
typedef unsigned int u32;

__device__ __forceinline__ u16 f2bf(float f) {
  u32 u = __builtin_bit_cast(u32, f);
  u32 r = (u + 0x7fffu + ((u >> 16) & 1u)) >> 16;
  return (u16)r;
}
__device__ __forceinline__ float bflo(u32 q) { return __builtin_bit_cast(float, q << 16); }
__device__ __forceinline__ float bfhi(u32 q) { return __builtin_bit_cast(float, q & 0xffff0000u); }

// ---------- prep: WpT[128][512] bf16 = (post_W @ lin_W)^T ; WpqT[256][128] bf16 = preW^T-reorg ; bp fp32 ----------
__global__ __launch_bounds__(256) void k_prep(const float* __restrict__ post_W,
    const float* __restrict__ post_b, const float* __restrict__ lin_W,
    const float* __restrict__ lin_b, const float* __restrict__ pre_W,
    u16* __restrict__ WpT, u16* __restrict__ WpqT, float* __restrict__ bp) {
  int idx = blockIdx.x * 256 + threadIdx.x;
  if (idx < 512 * 128) {
    int i = idx >> 7, j = idx & 127;
    float s = 0.f;
#pragma unroll 8
    for (int c = 0; c < 128; c++) s += post_W[i * 128 + c] * lin_W[c * 128 + j];
    WpT[j * 512 + i] = f2bf(s);
  } else if (idx < 512 * 128 + 256 * 128) {
    int u = idx - 512 * 128;
    int j = u >> 7, k = u & 127;
    float v = (j < 128) ? pre_W[k * 128 + j] : pre_W[(128 + k) * 128 + (j - 128)];
    WpqT[j * 128 + k] = f2bf(v);
  } else if (idx < 512 * 128 + 256 * 128 + 128) {
    int j = idx - (512 * 128 + 256 * 128);
    float s = lin_b[j];
    for (int c = 0; c < 128; c++) s += post_b[c] * lin_W[c * 128 + j];
    bp[j] = s;
  }
}

// ---------- convert x -> bf16 into Xcat[:, 0:128] (Xcat is [NN][512]) ----------
__global__ __launch_bounds__(256) void k_convert_x(const float* __restrict__ x,
                                                   u16* __restrict__ Xcat) {
  int tid = blockIdx.x * 256 + threadIdx.x;
  if (tid >= NN * 16) return;
  int row = tid >> 4;
  int col = (tid & 15) << 3;
  const float4 v0 = *(const float4*)(x + (size_t)row * 128 + col);
  const float4 v1 = *(const float4*)(x + (size_t)row * 128 + col + 4);
  u16 tmp[8] = {f2bf(v0.x), f2bf(v0.y), f2bf(v0.z), f2bf(v0.w),
                f2bf(v1.x), f2bf(v1.y), f2bf(v1.z), f2bf(v1.w)};
  *(bf16x8*)(Xcat + (size_t)row * 512 + col) = *(bf16x8*)tmp;
}

// ---------- MFMA GEMM helpers: K-major swizzled LDS tiles [128 rows][64 k] ----------
template <int KTOT, int LDA>
__device__ __forceinline__ void stage_tiles(const u16* __restrict__ A,
    const u16* __restrict__ BT, int row0, int n0, int k0,
    u16* __restrict__ As, u16* __restrict__ Bs, int t) {
#pragma unroll
  for (int it = 0; it < 4; ++it) {
    int c = t + it * 256;
    int row = c >> 3, ch = c & 7;
    int gr = row0 + row;
    bf16x8 v = {};
    if (gr < NN) v = *(const bf16x8*)(A + (size_t)gr * LDA + k0 + (ch << 3));
    *(bf16x8*)(As + row * 64 + ((ch ^ (row & 7)) << 3)) = v;
  }
#pragma unroll
  for (int it = 0; it < 4; ++it) {
    int c = t + it * 256;
    int n = c >> 3, ch = c & 7;
    bf16x8 v = *(const bf16x8*)(BT + (size_t)(n0 + n) * KTOT + k0 + (ch << 3));
    *(bf16x8*)(Bs + n * 64 + ((ch ^ (n & 7)) << 3)) = v;
  }
}

__device__ __forceinline__ bf16x8 ld_frag(const u16* __restrict__ S, int rowbase,
                                          int kk, int lane) {
  int r = rowbase + (lane & 15);
  int chunk = (kk >> 3) + (lane >> 4);
  int sw = chunk ^ (r & 7);
  return *(const bf16x8*)(S + r * 64 + (sw << 3));
}

// ---------- GEMM: PQb[N,256] bf16 = Xcat[:,0:128] @ WpqT^T ----------
__global__ __launch_bounds__(256) void k_gemm_pq(const u16* __restrict__ Xcat,
    const u16* __restrict__ WpqT, u16* __restrict__ PQb) {
  __shared__ u16 As[128 * 64];
  __shared__ u16 Bs[128 * 64];
  const int t = threadIdx.x;
  const int lane = t & 63, wid = t >> 6;
  const int wr = wid >> 1, wc = wid & 1;
  const int row0 = blockIdx.x * 128;
  const int n0 = blockIdx.y * 128;
  f32x4 acc[4][4] = {};
  for (int k0 = 0; k0 < 128; k0 += 64) {
    stage_tiles<128, 512>(Xcat, WpqT, row0, n0, k0, As, Bs, t);
    __syncthreads();
#pragma unroll
    for (int kk = 0; kk < 64; kk += 32) {
      bf16x8 af[4], bg[4];
#pragma unroll
      for (int m = 0; m < 4; ++m) af[m] = ld_frag(As, wr * 64 + m * 16, kk, lane);
#pragma unroll
      for (int n = 0; n < 4; ++n) bg[n] = ld_frag(Bs, wc * 64 + n * 16, kk, lane);
#pragma unroll
      for (int m = 0; m < 4; ++m)
#pragma unroll
        for (int n = 0; n < 4; ++n)
          acc[m][n] = __builtin_amdgcn_mfma_f32_16x16x32_bf16(af[m], bg[n], acc[m][n], 0, 0, 0);
    }
    __syncthreads();
  }
#pragma unroll
  for (int m = 0; m < 4; ++m) {
    int rb = row0 + wr * 64 + m * 16 + ((lane >> 4) << 2);
#pragma unroll
    for (int n = 0; n < 4; ++n) {
      int col = n0 + wc * 64 + n * 16 + (lane & 15);
#pragma unroll
      for (int r = 0; r < 4; ++r) {
        int row = rb + r;
        if (row < NN) PQb[(size_t)row * 256 + col] = f2bf(acc[m][n][r]);
      }
    }
  }
}

// ---------- GEMM: out[N,128] fp32 = relu(Xcat[N,512] @ WpT^T + bp) ----------
__global__ __launch_bounds__(256) void k_gemm_out(const u16* __restrict__ Xcat,
    const u16* __restrict__ WpT, const float* __restrict__ bp,
    float* __restrict__ out) {
  __shared__ u16 As[128 * 64];
  __shared__ u16 Bs[128 * 64];
  const int t = threadIdx.x;
  const int lane = t & 63, wid = t >> 6;
  const int wr = wid >> 1, wc = wid & 1;
  const int row0 = blockIdx.x * 128;
  f32x4 acc[4][4] = {};
  for (int k0 = 0; k0 < 512; k0 += 64) {
    stage_tiles<512, 512>(Xcat, WpT, row0, 0, k0, As, Bs, t);
    __syncthreads();
#pragma unroll
    for (int kk = 0; kk < 64; kk += 32) {
      bf16x8 af[4], bg[4];
#pragma unroll
      for (int m = 0; m < 4; ++m) af[m] = ld_frag(As, wr * 64 + m * 16, kk, lane);
#pragma unroll
      for (int n = 0; n < 4; ++n) bg[n] = ld_frag(Bs, wc * 64 + n * 16, kk, lane);
#pragma unroll
      for (int m = 0; m < 4; ++m)
#pragma unroll
        for (int n = 0; n < 4; ++n)
          acc[m][n] = __builtin_amdgcn_mfma_f32_16x16x32_bf16(af[m], bg[n], acc[m][n], 0, 0, 0);
    }
    __syncthreads();
  }
#pragma unroll
  for (int m = 0; m < 4; ++m) {
    int rb = row0 + wr * 64 + m * 16 + ((lane >> 4) << 2);
#pragma unroll
    for (int n = 0; n < 4; ++n) {
      int col = wc * 64 + n * 16 + (lane & 15);
      float bias = bp[col];
#pragma unroll
      for (int r = 0; r < 4; ++r) {
        int row = rb + r;
        if (row < NN) out[(size_t)row * 128 + col] = fmaxf(acc[m][n][r] + bias, 0.f);
      }
    }
  }
}

// ---------- bucket-granularity CSR build (no per-node precount, no memset) ----------
__global__ void k_zero256(int* __restrict__ bucket_cnt) {
  bucket_cnt[threadIdx.x] = 0;  // single block of 256
}

__global__ __launch_bounds__(256) void k_bucketcnt(const int* __restrict__ ei,
                                                   int* __restrict__ bucket_cnt) {
  __shared__ int hist[256];
  const int t = threadIdx.x;
  hist[t] = 0;
  __syncthreads();
  const int e0 = blockIdx.x * T1;
  const int ec = min(T1, EE - e0);
  for (int j = t; j < ec; j += 256) atomicAdd(&hist[ei[EE + e0 + j] >> 8], 1);
  __syncthreads();
  if (hist[t]) atomicAdd(&bucket_cnt[t], hist[t]);
}

__global__ void k_scanbucket(const int* __restrict__ bucket_cnt,
                             int* __restrict__ bucket_base,
                             int* __restrict__ bucket_cursor) {
  __shared__ int sd[256];
  int t = threadIdx.x;  // single block of 256
  int v = (t < NBKT) ? bucket_cnt[t] : 0;
  sd[t] = v;
  __syncthreads();
  for (int s = 1; s < 256; s <<= 1) {
    int tv = (t >= s) ? sd[t - s] : 0;
    __syncthreads();
    sd[t] += tv;
    __syncthreads();
  }
  int excl = sd[t] - v;
  bucket_base[t] = excl;       // bucket_base[NBKT] == EE lands here too (v=0 for t>=NBKT)
  bucket_cursor[t] = excl;
}

// ---------- pass 1: tile-sorted bucket scatter of packed (dst<<16|src) into ebuf ----------
__global__ __launch_bounds__(256) void k_bucket(const int* __restrict__ ei,
    int* __restrict__ bucket_cursor, u32* __restrict__ ebuf) {
  __shared__ u32 tilebuf[T1];
  __shared__ u32 gpos[T1];
  __shared__ int hist[256], scan_[256], runbase[256], ctr[256];
  const int t = threadIdx.x;
  const int e0 = blockIdx.x * T1;
  const int ecount = min(T1, EE - e0);
  hist[t] = 0;
  __syncthreads();
  u32 myp[16];
  int myb[16];
#pragma unroll
  for (int k = 0; k < 16; ++k) {
    int idx = t + k * 256;
    myp[k] = 0; myb[k] = 0;
    if (idx < ecount) {
      int e = e0 + idx;
      int s = ei[e], d = ei[EE + e];
      myp[k] = ((u32)d << 16) | (u32)s;
      int b = d >> 8;
      myb[k] = b;
      atomicAdd(&hist[b], 1);
    }
  }
  __syncthreads();
  int v = hist[t];
  scan_[t] = v;
  __syncthreads();
  for (int s_ = 1; s_ < 256; s_ <<= 1) {
    int tv = (t >= s_) ? scan_[t - s_] : 0;
    __syncthreads();
    scan_[t] += tv;
    __syncthreads();
  }
  int excl = scan_[t] - v;
  __syncthreads();
  scan_[t] = excl;
  ctr[t] = 0;
  if (v > 0) runbase[t] = atomicAdd(&bucket_cursor[t], v);
  __syncthreads();
#pragma unroll
  for (int k = 0; k < 16; ++k) {
    int idx = t + k * 256;
    if (idx < ecount) {
      int b = myb[k];
      int l = atomicAdd(&ctr[b], 1);
      int slot = scan_[b] + l;
      tilebuf[slot] = myp[k];
      gpos[slot] = (u32)(runbase[b] + l);
    }
  }
  __syncthreads();
  for (int j = t; j < ecount; j += 256) ebuf[gpos[j]] = tilebuf[j];
}

// ---------- pass 2: per-bucket LDS counting sort -> row_ptr + per-node CSR (u16 src) ----------
__global__ __launch_bounds__(256) void k_sortbucket(const u32* __restrict__ ebuf,
    const int* __restrict__ bucket_base, int* __restrict__ row_ptr,
    u16* __restrict__ csr_src) {
  __shared__ u16 sorted[CAP2];  // 16 KB
  __shared__ int hist[256], scan_[256], ctr[256];
  const int b = blockIdx.x;
  const int t = threadIdx.x;
  const int base = bucket_base[b];
  const int end = bucket_base[b + 1];
  const int count = end - base;
  hist[t] = 0;
  __syncthreads();
  for (int j = t; j < count; j += 256) atomicAdd(&hist[(ebuf[base + j] >> 16) & 255], 1);
  __syncthreads();
  int v = hist[t];
  scan_[t] = v;
  __syncthreads();
  for (int s_ = 1; s_ < 256; s_ <<= 1) {
    int tv = (t >= s_) ? scan_[t - s_] : 0;
    __syncthreads();
    scan_[t] += tv;
    __syncthreads();
  }
  int excl = scan_[t] - v;
  __syncthreads();
  scan_[t] = excl;
  ctr[t] = 0;
  int node = b * 256 + t;
  if (node < NN) row_ptr[node] = base + excl;
  if (b == NBKT - 1 && t == 0) row_ptr[NN] = EE;
  __syncthreads();
  if (count <= CAP2) {
    for (int j = t; j < count; j += 256) {
      u32 p = ebuf[base + j];
      int ln = (p >> 16) & 255;
      int l = atomicAdd(&ctr[ln], 1);
      sorted[scan_[ln] + l] = (u16)(p & 0xffffu);
    }
    __syncthreads();
    for (int j = t; j < count; j += 256) csr_src[base + j] = sorted[j];
  } else {
    // safety fallback (statistically unreachable): direct scatter, still correct
    for (int j = t; j < count; j += 256) {
      u32 p = ebuf[base + j];
      int ln = (p >> 16) & 255;
      int l = atomicAdd(&ctr[ln], 1);
      csr_src[base + scan_[ln] + l] = (u16)(p & 0xffffu);
    }
  }
}

// ---------- aggregation: one wave per node; unmasked 16/8/4-batches + serial tail ----------
__global__ __launch_bounds__(256) void k_aggr(const u16* __restrict__ PQb,
    const float* __restrict__ pre_b, const int* __restrict__ row_ptr,
    const u16* __restrict__ csr_src, u16* __restrict__ Xcat) {
  int wid = (blockIdx.x * 256 + threadIdx.x) >> 6;
  int lane = threadIdx.x & 63;
  if (wid >= NN) return;
  int r0 = row_ptr[wid], r1 = row_ptr[wid + 1];
  int c = lane * 2;
  const u16* Qbase = PQb + 128 + c;  // row s -> Qbase + s*256
  float sx = 0.f, sy = 0.f, mxx = -FLT_MAX, mxy = -FLT_MAX;
  int i = r0;
  for (; i + 16 <= r1; i += 16) {
    int s[16];
#pragma unroll
    for (int k = 0; k < 16; ++k) s[k] = csr_src[i + k];
    u32 q[16];
#pragma unroll
    for (int k = 0; k < 16; ++k) q[k] = *(const u32*)(Qbase + (size_t)s[k] * 256);
#pragma unroll
    for (int k = 0; k < 16; ++k) {
      float qx = bflo(q[k]), qy = bfhi(q[k]);
      sx += qx; sy += qy;
      mxx = fmaxf(mxx, qx); mxy = fmaxf(mxy, qy);
    }
  }
  if (i + 8 <= r1) {
    int s[8];
#pragma unroll
    for (int k = 0; k < 8; ++k) s[k] = csr_src[i + k];
    u32 q[8];
#pragma unroll
    for (int k = 0; k < 8; ++k) q[k] = *(const u32*)(Qbase + (size_t)s[k] * 256);
#pragma unroll
    for (int k = 0; k < 8; ++k) {
      float qx = bflo(q[k]), qy = bfhi(q[k]);
      sx += qx; sy += qy;
      mxx = fmaxf(mxx, qx); mxy = fmaxf(mxy, qy);
    }
    i += 8;
  }
  if (i + 4 <= r1) {
    int s[4];
#pragma unroll
    for (int k = 0; k < 4; ++k) s[k] = csr_src[i + k];
    u32 q[4];
#pragma unroll
    for (int k = 0; k < 4; ++k) q[k] = *(const u32*)(Qbase + (size_t)s[k] * 256);
#pragma unroll
    for (int k = 0; k < 4; ++k) {
      float qx = bflo(q[k]), qy = bfhi(q[k]);
      sx += qx; sy += qy;
      mxx = fmaxf(mxx, qx); mxy = fmaxf(mxy, qy);
    }
    i += 4;
  }
  for (; i < r1; ++i) {
    int s = csr_src[i];
    u32 q = *(const u32*)(Qbase + (size_t)s * 256);
    float qx = bflo(q), qy = bfhi(q);
    sx += qx; sy += qy;
    mxx = fmaxf(mxx, qx); mxy = fmaxf(mxy, qy);
  }
  u32 pu = *(const u32*)(PQb + (size_t)wid * 256 + c);
  float2 b = *(const float2*)(pre_b + c);
  float px = bflo(pu) + b.x;
  float py = bfhi(pu) + b.y;
  int deg = r1 - r0;
  float vm_x = 0.f, vm_y = 0.f, vx_x = 0.f, vx_y = 0.f, vs_x = 0.f, vs_y = 0.f;
  if (deg > 0) {
    float inv = 1.0f / (float)deg;
    vm_x = px + sx * inv;          vm_y = py + sy * inv;
    vx_x = px + mxx;               vx_y = py + mxy;
    vs_x = (float)deg * px + sx;   vs_y = (float)deg * py + sy;
  }
  u16* arow = Xcat + (size_t)wid * 512 + 128;
  *(u32*)(arow + c)       = (u32)f2bf(vm_x) | ((u32)f2bf(vm_y) << 16);
  *(u32*)(arow + 128 + c) = (u32)f2bf(vx_x) | ((u32)f2bf(vx_y) << 16);
  *(u32*)(arow + 256 + c) = (u32)f2bf(vs_x) | ((u32)f2bf(vs_y) << 16);
}

extern "C" void kernel_launch(void* const* d_in, const int* in_sizes, int n_in,
                              void* d_out, int out_size, void* d_ws, size_t ws_size,
                              hipStream_t stream) {
  const float* x      = (const float*)d_in[0];
  const int*   ei     = (const int*)d_in[1];   // [0..E)=src, [E..2E)=dst
  const float* pre_W  = (const float*)d_in[2];
  const float* pre_b  = (const float*)d_in[3];
  const float* post_W = (const float*)d_in[4];
  const float* post_b = (const float*)d_in[5];
  const float* lin_W  = (const float*)d_in[6];
  const float* lin_b  = (const float*)d_in[7];
  float* out = (float*)d_out;

  char* ws = (char*)d_ws;
  size_t off = 0;
  auto alloc = [&](size_t bytes) { size_t o = off; off = (off + bytes + 511) & ~(size_t)511; return o; };
  u16*   Xcat    = (u16*)(ws + alloc((size_t)NN * 512 * 2));
  u16*   PQb     = (u16*)(ws + alloc((size_t)NN * 256 * 2));
  u16*   WpT     = (u16*)(ws + alloc(128 * 512 * 2));
  u16*   WpqT    = (u16*)(ws + alloc(256 * 128 * 2));
  float* bp      = (float*)(ws + alloc(128 * 4));
  int*   row_ptr = (int*)(ws + alloc((size_t)(NN + 1) * 4));
  int*   bucket_cnt    = (int*)(ws + alloc(256 * 4));
  int*   bucket_base   = (int*)(ws + alloc(257 * 4));
  int*   bucket_cursor = (int*)(ws + alloc(256 * 4));
  u32*   ebuf    = (u32*)(ws + alloc((size_t)EE * 4));
  u16*   csr_src = (u16*)(ws + alloc((size_t)EE * 2));
  (void)ws_size; (void)in_sizes; (void)n_in; (void)out_size;

  const int NB_M = (NN + 127) / 128;       // 391
  const int NB_T = (EE + T1 - 1) / T1;     // 196

  k_prep<<<(512 * 128 + 256 * 128 + 128 + 255) / 256, 256, 0, stream>>>(
      post_W, post_b, lin_W, lin_b, pre_W, WpT, WpqT, bp);
  k_convert_x<<<(NN * 16 + 255) / 256, 256, 0, stream>>>(x, Xcat);
  k_zero256<<<1, 256, 0, stream>>>(bucket_cnt);
  k_bucketcnt<<<NB_T, 256, 0, stream>>>(ei, bucket_cnt);
  k_gemm_pq<<<dim3(NB_M, 2), 256, 0, stream>>>(Xcat, WpqT, PQb);
  k_scanbucket<<<1, 256, 0, stream>>>(bucket_cnt, bucket_base, bucket_cursor);
  k_bucket<<<NB_T, 256, 0, stream>>>(ei, bucket_cursor, ebuf);
  k_sortbucket<<<NBKT, 256, 0, stream>>>(ebuf, bucket_base, row_ptr, csr_src);
  k_aggr<<<(NN * 64 + 255) / 256, 256, 0, stream>>>(PQb, pre_b, row_ptr, csr_src, Xcat);
  k_gemm_out<<<NB_M, 256, 0, stream>>>(Xcat, WpT, bp, out);
}